// Round 5
// baseline (1642.467 us; speedup 1.0000x reference)
//
#include <hip/hip_runtime.h>
#include <hip/hip_bf16.h>

#define NROW  64
#define KDIM  1024
#define NDIM  1024

typedef short bf16x8 __attribute__((ext_vector_type(8)));
typedef float f32x4  __attribute__((ext_vector_type(4)));

// fp32 -> bf16 round-half-up, two at once: (u + 0x8000) >> 16, packed with one v_perm_b32.
__device__ __forceinline__ unsigned pk2bf(float lo, float hi) {
  unsigned ulo = __builtin_bit_cast(unsigned, lo) + 0x8000u;
  unsigned uhi = __builtin_bit_cast(unsigned, hi) + 0x8000u;
  return __builtin_amdgcn_perm(uhi, ulo, 0x07060302u);
}

// out[m, r, n] = sum_k x[m, r, k] * W[r, k, n] + bias[r, n]
// per r: GEMM M=512 (batch), K=1024, N=1024.
// v4: 256x256 tile, 512 threads (2x4 waves, wave tile 128x64 via 8x4 MFMA 16x16x32 bf16),
//     DOUBLE-BUFFERED LDS with ONE barrier per K-step: iter ks reads buf[ks&1] (written
//     last iter), converts+writes slab ks+1 into buf[ks^1] and issues loads for slab ks+2
//     under the MFMA shadow. Single __syncthreads per step is sufficient (lgkm drains at
//     barrier; no wave overwrites a buffer until all finished reading it last step).
//     T5 setprio around MFMA cluster. launch_bounds(512,4) pins VGPR<=128 -> 2 blocks/CU.
__global__ __launch_bounds__(512, 4) void Group_MLP_kernel(
    const float* __restrict__ x, const float* __restrict__ W,
    const float* __restrict__ bias, float* __restrict__ out) {
  // ---- block mapping: 512 blocks; XCD gets r in [xcd*8, xcd*8+8); 8 blocks per r.
  const int g   = blockIdx.x;
  const int xcd = g & 7;
  const int idx = g >> 3;          // 0..63
  const int r   = xcd * 8 + (idx >> 3);
  const int mb  = (idx >> 2) & 1;  // 0..1
  const int nb  = idx & 3;         // 0..3
  const int m0 = mb * 256;
  const int n0 = nb * 256;

  const int t    = threadIdx.x;    // 0..511
  const int l    = t & 63;
  const int wave = t >> 6;         // 0..7
  const int wm   = wave >> 2, wn = wave & 3;   // 2 x 4 -> wave tile 128m x 64n
  const int lm   = l & 15, quad = l >> 4;

  // LDS: fragment-linear 16 B chunks, two buffers.
  // buf0: A chunks [0,1024), B chunks [1024,2048).  buf1: +2048 chunks (+32 KiB).
  // A chunk p = mt*64 + q*16 + lm  holds  x[m0 + mt*16 + lm][k0 + q*8 .. +7]   (mt 0..15)
  // B chunk p = nt*64 + quad*16 + lm holds W[k0 + quad*8 .. +7][n0 + nt*16 + lm] (nt 0..15)
  //   stored at PHYSICAL chunk p ^ ((p>>6)&7)
  __shared__ uint4 smem4[4096];   // 64 KiB
  uint2* s2 = (uint2*)smem4;      // 8 B half-chunks

  // ---- A staging: half-chunk c = i*512 + t, i = 0..3 (rows m0 + i*64 + maBase)
  const int maBase = ((t >> 7) << 4) | ((t >> 1) & 15);            // 0..63
  const int kof    = (((t >> 5) & 3) << 3) | ((t & 1) << 2);       // 0..28
  const float* gA[4];
  #pragma unroll
  for (int i = 0; i < 4; ++i)
    gA[i] = x + (size_t)(m0 + i * 64 + maBase) * (NROW * KDIM) + r * KDIM + kof;

  // ---- B staging: thread (n4 in 0..63, qh in 0..7) loads W[qh*4+j][n0+n4*4 .. +3], j=0..3.
  // Lane-bit map is bank-pair-bijective within fixed 16-lane hw groups (verified: conflicts=0).
  const int n4 = ((t >> 3) & 1) | (((t >> 5) & 1) << 1) | (((t >> 1) & 1) << 2)
               | (((t >> 2) & 1) << 3) | (((t >> 4) & 1) << 4) | (((t >> 6) & 1) << 5);
  const int qh = (t & 1) | (((t >> 7) & 1) << 1) | (((t >> 8) & 1) << 2);
  const float* gB[4];
  #pragma unroll
  for (int j = 0; j < 4; ++j)
    gB[j] = W + (size_t)r * (KDIM * NDIM) + (qh * 4 + j) * NDIM + n0 + n4 * 4;
  const int baseP  = (n4 >> 2) * 64 + ((qh >> 1) & 3) * 16 + (n4 & 3) * 4;
  const int swBase = baseP ^ ((n4 >> 2) & 7);   // XOR swizzle, cc-independent
  const int hB     = qh & 1;                    // which 8B half of the 16B chunk
  const int bW     = 2048 | (swBase << 1) | hB; // half-chunk addr in buf0 B region

  // ---- fragment read indices (16 B physical chunk units, buf0)
  int aIdx[8], bIdx[4];
  #pragma unroll
  for (int i = 0; i < 8; ++i) aIdx[i] = (wm * 8 + i) * 64 + l;
  #pragma unroll
  for (int j = 0; j < 4; ++j) {
    int grp = wn * 4 + j;                        // 0..15
    bIdx[j] = 1024 + grp * 64 + (l ^ (grp & 7)); // physical chunk of logical grp*64 + l
  }

  f32x4 acc[8][4];
  #pragma unroll
  for (int i = 0; i < 8; ++i)
    #pragma unroll
    for (int j = 0; j < 4; ++j)
      acc[i][j] = {0.f, 0.f, 0.f, 0.f};

  float4 rawA[4], rawB[4];   // slab ks+1, fp32 in flight
  uint2  cvtA[4], cvtB[4];   // converted slab, ready to write

#define CONVERT_ALL()                                                              \
  {                                                                                \
    _Pragma("unroll")                                                              \
    for (int i = 0; i < 4; ++i) {                                                  \
      cvtA[i].x = pk2bf(rawA[i].x, rawA[i].y);                                     \
      cvtA[i].y = pk2bf(rawA[i].z, rawA[i].w);                                     \
    }                                                                              \
    cvtB[0].x = pk2bf(rawB[0].x, rawB[1].x); cvtB[0].y = pk2bf(rawB[2].x, rawB[3].x); \
    cvtB[1].x = pk2bf(rawB[0].y, rawB[1].y); cvtB[1].y = pk2bf(rawB[2].y, rawB[3].y); \
    cvtB[2].x = pk2bf(rawB[0].z, rawB[1].z); cvtB[2].y = pk2bf(rawB[2].z, rawB[3].z); \
    cvtB[3].x = pk2bf(rawB[0].w, rawB[1].w); cvtB[3].y = pk2bf(rawB[2].w, rawB[3].w); \
  }

#define ADVANCE_LOAD()                                                             \
  {                                                                                \
    _Pragma("unroll")                                                              \
    for (int i = 0; i < 4; ++i) { gA[i] += 32; rawA[i] = *(const float4*)(gA[i]); } \
    _Pragma("unroll")                                                              \
    for (int j = 0; j < 4; ++j) { gB[j] += 32 * NDIM; rawB[j] = *(const float4*)(gB[j]); } \
  }

  // ---- prologue: load slab 0, convert, write into buf0; issue loads for slab 1.
  #pragma unroll
  for (int i = 0; i < 4; ++i) rawA[i] = *(const float4*)(gA[i]);
  #pragma unroll
  for (int j = 0; j < 4; ++j) rawB[j] = *(const float4*)(gB[j]);
  CONVERT_ALL();
  #pragma unroll
  for (int i = 0; i < 4; ++i) s2[i * 512 + t] = cvtA[i];
  #pragma unroll
  for (int cc = 0; cc < 4; ++cc) s2[bW ^ (cc << 1)] = cvtB[cc];
  ADVANCE_LOAD();
  __syncthreads();

  // ---- main loop: one barrier per K-step, double-buffered.
  // STEP(ks, CUR, NXT): read frags from buf CUR, convert+write slab ks+1 to buf NXT,
  //                     issue loads slab ks+2, MFMA, barrier.
#define STEP(KS, CUR, NXT)                                                         \
  {                                                                                \
    bf16x8 af[8], bfr[4];                                                          \
    _Pragma("unroll")                                                              \
    for (int i = 0; i < 8; ++i)                                                    \
      af[i]  = __builtin_bit_cast(bf16x8, smem4[aIdx[i] + (CUR) * 2048]);          \
    _Pragma("unroll")                                                              \
    for (int j = 0; j < 4; ++j)                                                    \
      bfr[j] = __builtin_bit_cast(bf16x8, smem4[bIdx[j] + (CUR) * 2048]);          \
    if ((KS) < 31) {                                                               \
      CONVERT_ALL();                                                               \
      _Pragma("unroll")                                                            \
      for (int i = 0; i < 4; ++i) s2[i * 512 + t + (NXT) * 4096] = cvtA[i];        \
      _Pragma("unroll")                                                            \
      for (int cc = 0; cc < 4; ++cc) s2[(bW ^ (cc << 1)) + (NXT) * 4096] = cvtB[cc]; \
      if ((KS) < 30) ADVANCE_LOAD();                                               \
    }                                                                              \
    __builtin_amdgcn_s_setprio(1);                                                 \
    _Pragma("unroll")                                                              \
    for (int j = 0; j < 4; ++j)                                                    \
      _Pragma("unroll")                                                            \
      for (int i = 0; i < 8; ++i)                                                  \
        acc[i][j] = __builtin_amdgcn_mfma_f32_16x16x32_bf16(af[i], bfr[j], acc[i][j], 0, 0, 0); \
    __builtin_amdgcn_s_setprio(0);                                                 \
    __syncthreads();                                                               \
  }

  for (int kp = 0; kp < 16; ++kp) {
    STEP(2 * kp,     0, 1);
    STEP(2 * kp + 1, 1, 0);
  }

#undef STEP
#undef ADVANCE_LOAD
#undef CONVERT_ALL

  // ---- epilogue: C/D layout col = lane&15, row = quad*4 + reg
  const int nColBase = n0 + wn * 64 + lm;
  const int mRowBase = m0 + wm * 128 + quad * 4;
  #pragma unroll
  for (int j = 0; j < 4; ++j) {
    int n = nColBase + j * 16;
    float bv = bias[r * NDIM + n];
    #pragma unroll
    for (int i = 0; i < 8; ++i) {
      int mr = mRowBase + i * 16;
      #pragma unroll
      for (int v = 0; v < 4; ++v) {
        out[(size_t)(mr + v) * (NROW * NDIM) + r * NDIM + n] = acc[i][j][v] + bv;
      }
    }
  }
}

extern "C" void kernel_launch(void* const* d_in, const int* in_sizes, int n_in,
                              void* d_out, int out_size, void* d_ws, size_t ws_size,
                              hipStream_t stream) {
  const float* x    = (const float*)d_in[0];
  const float* W    = (const float*)d_in[1];
  const float* bias = (const float*)d_in[2];
  float* out        = (float*)d_out;
  dim3 grid(512), block(512);
  hipLaunchKernelGGL(Group_MLP_kernel, grid, block, 0, stream, x, W, bias, out);
}